// Round 2
// baseline (1039.094 us; speedup 1.0000x reference)
//
#include <hip/hip_runtime.h>
#include <math.h>

#define NP 125
#define NC 21
#define TPB 256
#define THRESH 0.3f

__global__ void mbloss_init(float* acc, int* nposAcc) {
    acc[0] = 0.f; acc[1] = 0.f; acc[2] = 0.f;
    *nposAcc = 0;
}

__device__ inline float wredsum(float v) {
#pragma unroll
    for (int off = 32; off > 0; off >>= 1) v += __shfl_down(v, off, 64);
    return v;
}

__global__ void __launch_bounds__(TPB) mbloss_main(
    const float* __restrict__ locs, const float* __restrict__ scores,
    const float* __restrict__ target, const float* __restrict__ priors,
    float* __restrict__ acc, int* __restrict__ nposAcc) {

    __shared__ float s_sc[NP * NC];   // 2625 floats
    __shared__ float s_lc[NP * 6];    // 750
    __shared__ float s_pr[NP * 4];    // 500
    __shared__ float s_iou[NP];
    __shared__ float s_sort[128];
    __shared__ float s_red[4][4];
    __shared__ int   s_best;
    __shared__ int   s_npos;
    __shared__ float s_t[8];

    const int b    = blockIdx.x;
    const int tid  = threadIdx.x;
    const int wave = tid >> 6;
    const int lane = tid & 63;

    // ---- stage inputs into LDS (coalesced) ----
    if (tid < 8) s_t[tid] = target[(size_t)b * 8 + tid];
    for (int i = tid; i < NP * 4; i += TPB) s_pr[i] = priors[i];
    {
        const float* srow = scores + (size_t)b * (NP * NC);
        for (int i = tid; i < NP * NC; i += TPB) s_sc[i] = srow[i];
        const float* lrow = locs + (size_t)b * (NP * 6);
        for (int i = tid; i < NP * 6; i += TPB) s_lc[i] = lrow[i];
    }
    __syncthreads();

    const float bx = s_t[0], by = s_t[1], bw = s_t[2], bh = s_t[3];

    // ---- per-prior IoU ----
    if (tid < NP) {
        const float pcx = s_pr[tid * 4 + 0], pcy = s_pr[tid * 4 + 1];
        const float pw  = s_pr[tid * 4 + 2], ph  = s_pr[tid * 4 + 3];
        float iw = fminf(bx + bw * 0.5f, pcx + pw * 0.5f) -
                   fmaxf(bx - bw * 0.5f, pcx - pw * 0.5f);
        float ih = fminf(by + bh * 0.5f, pcy + ph * 0.5f) -
                   fmaxf(by - bh * 0.5f, pcy - ph * 0.5f);
        iw = fmaxf(iw, 0.f); ih = fmaxf(ih, 0.f);
        float inter = iw * ih;
        s_iou[tid] = inter / (bw * bh + pw * ph - inter);
    }
    __syncthreads();

    // ---- argmax over 125 ious, first-index tie-break (wave 0) ----
    if (wave == 0) {
        float v  = (tid < NP) ? s_iou[tid] : -1.f;
        int   ix = tid;
        float v2 = (tid + 64 < NP) ? s_iou[tid + 64] : -1.f;
        if (v2 > v) { v = v2; ix = tid + 64; }
#pragma unroll
        for (int off = 32; off > 0; off >>= 1) {
            float vo = __shfl_down(v, off, 64);
            int   io = __shfl_down(ix, off, 64);
            if (vo > v || (vo == v && io < ix)) { v = vo; ix = io; }
        }
        if (lane == 0) s_best = ix;
    }
    __syncthreads();
    const int best = s_best;

    // ---- per-prior losses ----
    float sl1 = 0.f, angsq = 0.f, confpos = 0.f, nposf = 0.f;
    if (tid < NP) {
        const bool pos = (tid == best) || (s_iou[tid] >= THRESH);
        const float* sc = &s_sc[tid * NC];
        float m = sc[0];
#pragma unroll
        for (int c = 1; c < NC; ++c) m = fmaxf(m, sc[c]);
        float ssum = 0.f;
#pragma unroll
        for (int c = 0; c < NC; ++c) ssum += expf(sc[c] - m);
        float lse = m + logf(ssum);
        int lbl = pos ? (int)s_t[7] : 0;
        float conf = lse - sc[lbl];
        if (pos) {
            nposf   = 1.f;
            confpos = conf;
            const float pcx = s_pr[tid * 4 + 0], pcy = s_pr[tid * 4 + 1];
            const float pw  = s_pr[tid * 4 + 2], ph  = s_pr[tid * 4 + 3];
            float g0 = (bx - pcx) / (pw * 0.1f);
            float g1 = (by - pcy) / (ph * 0.1f);
            float g2 = logf(bw / pw) * 5.f;
            float g3 = logf(bh / ph) * 5.f;
            const float* L = &s_lc[tid * 6];
            float d0 = L[0] - g0, d1 = L[1] - g1, d2 = L[2] - g2, d3 = L[3] - g3;
#define SL1(d) (fabsf(d) < 1.f ? 0.5f * (d) * (d) : fabsf(d) - 0.5f)
            sl1 = SL1(d0) + SL1(d1) + SL1(d2) + SL1(d3);
            float da0 = L[4] - s_t[5], da1 = L[5] - s_t[6];
            angsq = da0 * da0 + da1 * da1;
        }
        s_sort[tid] = pos ? 0.f : conf;   // conf_neg
    } else if (tid < 128) {
        s_sort[tid] = -1.f;               // pad below all real values (>=0)
    }

    // ---- block-reduce 4 partials ----
    float r0 = wredsum(sl1), r1 = wredsum(angsq), r2 = wredsum(confpos), r3 = wredsum(nposf);
    if (lane == 0) { s_red[wave][0] = r0; s_red[wave][1] = r1; s_red[wave][2] = r2; s_red[wave][3] = r3; }
    __syncthreads();
    float tot_sl1 = 0.f, tot_ang = 0.f, tot_cp = 0.f;
    int npos_local = 0;
    if (tid == 0) {
        float tn = 0.f;
        for (int w = 0; w < 4; ++w) {
            tot_sl1 += s_red[w][0]; tot_ang += s_red[w][1];
            tot_cp  += s_red[w][2]; tn      += s_red[w][3];
        }
        npos_local = (int)(tn + 0.5f);
        s_npos = npos_local;
    }

    // ---- bitonic sort s_sort[0..127] descending ----
    for (int k = 2; k <= 128; k <<= 1) {
        for (int j = k >> 1; j > 0; j >>= 1) {
            __syncthreads();
            if (tid < 64) {
                int ix = ((tid & ~(j - 1)) << 1) | (tid & (j - 1));
                int pr = ix | j;
                float a = s_sort[ix], c = s_sort[pr];
                bool up = ((ix & k) == 0);           // descending region
                bool sw = up ? (a < c) : (a > c);
                if (sw) { s_sort[ix] = c; s_sort[pr] = a; }
            }
        }
    }
    __syncthreads();

    // ---- hard-negative sum: top min(3*n_pos, 125) ----
    const int npb = s_npos;
    int kk = 3 * npb; if (kk > NP) kk = NP;
    float hv = (tid < kk) ? s_sort[tid] : 0.f;   // kk <= 125 < 128
    float hr = wredsum(hv);
    if (lane == 0) s_red[wave][0] = hr;
    __syncthreads();
    if (tid == 0) {
        float hsum = s_red[0][0] + s_red[1][0] + s_red[2][0] + s_red[3][0];
        atomicAdd(&acc[0], tot_cp + hsum);
        atomicAdd(&acc[1], tot_sl1);
        atomicAdd(&acc[2], tot_ang);
        atomicAdd(nposAcc, npos_local);
    }
}

__global__ void mbloss_fin(const float* __restrict__ acc,
                           const int* __restrict__ nposAcc,
                           float* __restrict__ out) {
    float npt  = (float)(*nposAcc);
    float conf = acc[0] / npt;
    float loc  = acc[1] / (npt * 4.f);
    float ang  = 25.f * acc[2] / (npt * 2.f);
    out[0] = conf; out[1] = loc; out[2] = ang; out[3] = conf + loc + ang;
}

extern "C" void kernel_launch(void* const* d_in, const int* in_sizes, int n_in,
                              void* d_out, int out_size, void* d_ws, size_t ws_size,
                              hipStream_t stream) {
    const float* locs   = (const float*)d_in[0];
    const float* scores = (const float*)d_in[1];
    const float* target = (const float*)d_in[2];
    const float* priors = (const float*)d_in[3];
    float* out = (float*)d_out;

    float* acc     = (float*)d_ws;
    int*   nposAcc = (int*)((char*)d_ws + 16);

    const int batch = in_sizes[2] / 8;   // target is (B,1,8)

    mbloss_init<<<1, 1, 0, stream>>>(acc, nposAcc);
    mbloss_main<<<batch, TPB, 0, stream>>>(locs, scores, target, priors, acc, nposAcc);
    mbloss_fin<<<1, 1, 0, stream>>>(acc, nposAcc, out);
}

// Round 3
// 283.359 us; speedup vs baseline: 3.6671x; 3.6671x over previous
//
#include <hip/hip_runtime.h>
#include <math.h>

#define NP 125
#define NC 21
#define TPB 256
#define WPB 4            // waves per block
#define THRESH 0.3f

// ---------------- main: one wave per batch row, no barriers, no atomics ----------------
__global__ void __launch_bounds__(TPB) mbloss_main(
    const float* __restrict__ locs, const float* __restrict__ scores,
    const float* __restrict__ target, const float* __restrict__ priors,
    float4* __restrict__ partials, int batch, int totw) {

    __shared__ float s_sc[WPB][NP * NC];   // 4 x 10500 B = 42000 B

    const int tid  = threadIdx.x;
    const int wave = tid >> 6;
    const int lane = tid & 63;
    float* sc = s_sc[wave];
    const int wgid = blockIdx.x * WPB + wave;

    // priors in registers: lane owns priors p0=lane and p1=lane+64
    const int  p1 = lane + 64;
    const bool v1 = (p1 < NP);
    const float4* pr4 = (const float4*)priors;
    float4 P0 = pr4[lane];
    float4 P1 = v1 ? pr4[p1] : make_float4(0.f, 0.f, 1.f, 1.f);

    float acc_conf = 0.f, acc_sl1 = 0.f, acc_ang = 0.f, acc_np = 0.f;

    for (int r = wgid; r < batch; r += totw) {
        // ---- stage score row into this wave's LDS slice (coalesced) ----
        const float* srow = scores + (size_t)r * (NP * NC);
#pragma unroll
        for (int it = 0; it < 41; ++it) sc[it * 64 + lane] = srow[it * 64 + lane];
        if (lane == 0) sc[2624] = srow[2624];

        // ---- target (wave-uniform -> scalar loads) ----
        const float* t = target + (size_t)r * 8;
        const float bx = t[0], by = t[1], bw = t[2], bh = t[3];
        const float sa = t[5], ca = t[6];
        const int lblT = (int)t[7];

        // ---- IoU for p0, p1 ----
        float iou0, iou1 = -1.f;
        {
            float iw = fminf(bx + bw * 0.5f, P0.x + P0.z * 0.5f) -
                       fmaxf(bx - bw * 0.5f, P0.x - P0.z * 0.5f);
            float ih = fminf(by + bh * 0.5f, P0.y + P0.w * 0.5f) -
                       fmaxf(by - bh * 0.5f, P0.y - P0.w * 0.5f);
            iw = fmaxf(iw, 0.f); ih = fmaxf(ih, 0.f);
            float inter = iw * ih;
            iou0 = inter / (bw * bh + P0.z * P0.w - inter);
        }
        if (v1) {
            float iw = fminf(bx + bw * 0.5f, P1.x + P1.z * 0.5f) -
                       fmaxf(bx - bw * 0.5f, P1.x - P1.z * 0.5f);
            float ih = fminf(by + bh * 0.5f, P1.y + P1.w * 0.5f) -
                       fmaxf(by - bh * 0.5f, P1.y - P1.w * 0.5f);
            iw = fmaxf(iw, 0.f); ih = fmaxf(ih, 0.f);
            float inter = iw * ih;
            iou1 = inter / (bw * bh + P1.z * P1.w - inter);
        }

        // ---- argmax (first-index tie-break), butterfly so all lanes agree ----
        float bv = iou0; int bi = lane;
        if (iou1 > bv) { bv = iou1; bi = p1; }
#pragma unroll
        for (int off = 1; off < 64; off <<= 1) {
            float vo = __shfl_xor(bv, off, 64);
            int   io = __shfl_xor(bi, off, 64);
            if (vo > bv || (vo == bv && io < bi)) { bv = vo; bi = io; }
        }
        const int best = bi;

        const bool pos0 = (lane == best) || (iou0 >= THRESH);
        const bool pos1 = v1 && ((p1 == best) || (iou1 >= THRESH));
        const int npos = __popcll(__ballot(pos0)) + __popcll(__ballot(pos1));
        acc_np += (pos0 ? 1.f : 0.f) + (pos1 ? 1.f : 0.f);

        // ---- logsumexp + conf per prior (LDS reads, stride-21 = bank permutation) ----
        float conf0, conf1 = 0.f;
        {
            const float* s0 = sc + lane * NC;
            float m = s0[0];
#pragma unroll
            for (int c = 1; c < NC; ++c) m = fmaxf(m, s0[c]);
            float ss = 0.f;
#pragma unroll
            for (int c = 0; c < NC; ++c) ss += expf(s0[c] - m);
            conf0 = (m + logf(ss)) - s0[pos0 ? lblT : 0];
        }
        if (v1) {
            const float* s1 = sc + p1 * NC;
            float m = s1[0];
#pragma unroll
            for (int c = 1; c < NC; ++c) m = fmaxf(m, s1[c]);
            float ss = 0.f;
#pragma unroll
            for (int c = 0; c < NC; ++c) ss += expf(s1[c] - m);
            conf1 = (m + logf(ss)) - s1[pos1 ? lblT : 0];
        }

        // ---- positive-prior losses (locs fetched on demand) ----
#define SL1(d) (fabsf(d) < 1.f ? 0.5f * (d) * (d) : fabsf(d) - 0.5f)
        if (pos0) {
            acc_conf += conf0;
            const float* L = locs + (size_t)r * (NP * 6) + lane * 6;
            float g0 = (bx - P0.x) / (P0.z * 0.1f);
            float g1 = (by - P0.y) / (P0.w * 0.1f);
            float g2 = logf(bw / P0.z) * 5.f;
            float g3 = logf(bh / P0.w) * 5.f;
            float d0 = L[0] - g0, d1 = L[1] - g1, d2 = L[2] - g2, d3 = L[3] - g3;
            acc_sl1 += SL1(d0) + SL1(d1) + SL1(d2) + SL1(d3);
            float a0 = L[4] - sa, a1 = L[5] - ca;
            acc_ang += a0 * a0 + a1 * a1;
        }
        if (pos1) {
            acc_conf += conf1;
            const float* L = locs + (size_t)r * (NP * 6) + p1 * 6;
            float g0 = (bx - P1.x) / (P1.z * 0.1f);
            float g1 = (by - P1.y) / (P1.w * 0.1f);
            float g2 = logf(bw / P1.z) * 5.f;
            float g3 = logf(bh / P1.w) * 5.f;
            float d0 = L[0] - g0, d1 = L[1] - g1, d2 = L[2] - g2, d3 = L[3] - g3;
            acc_sl1 += SL1(d0) + SL1(d1) + SL1(d2) + SL1(d3);
            float a0 = L[4] - sa, a1 = L[5] - ca;
            acc_ang += a0 * a0 + a1 * a1;
        }

        // ---- register bitonic sort, 128 virtual elems, descending ----
        float x0 = pos0 ? 0.f : conf0;                       // conf_neg >= 0 always
        float x1 = v1 ? (pos1 ? 0.f : conf1) : -1.f;         // pads sort last
#pragma unroll
        for (int k = 2; k <= 128; k <<= 1) {
#pragma unroll
            for (int j = k >> 1; j >= 1; j >>= 1) {
                if (j == 64) {                               // cross-register, same lane
                    float a = fmaxf(x0, x1), b = fminf(x0, x1);
                    x0 = a; x1 = b;
                } else {
                    bool lower = (lane & j) == 0;
                    bool d0 = ((lane & k) == 0);
                    bool d1 = (((lane + 64) & k) == 0);
                    float o0 = __shfl_xor(x0, j, 64);
                    float o1 = __shfl_xor(x1, j, 64);
                    x0 = (lower == d0) ? fmaxf(x0, o0) : fminf(x0, o0);
                    x1 = (lower == d1) ? fmaxf(x1, o1) : fminf(x1, o1);
                }
            }
        }

        // ---- hard-negative top-k (k = min(3*npos, 125)), per-lane accumulate ----
        int kk = 3 * npos; if (kk > NP) kk = NP;
        acc_conf += (lane < kk ? x0 : 0.f) + (lane + 64 < kk ? x1 : 0.f);
    }

    // ---- wave reduction, one float4 store per wave ----
#pragma unroll
    for (int off = 1; off < 64; off <<= 1) {
        acc_conf += __shfl_xor(acc_conf, off, 64);
        acc_sl1  += __shfl_xor(acc_sl1,  off, 64);
        acc_ang  += __shfl_xor(acc_ang,  off, 64);
        acc_np   += __shfl_xor(acc_np,   off, 64);
    }
    if (lane == 0) partials[wgid] = make_float4(acc_conf, acc_sl1, acc_ang, acc_np);
}

// ---------------- final reduce: one block ----------------
__global__ void __launch_bounds__(256) mbloss_fin(const float4* __restrict__ partials,
                                                  int n, float* __restrict__ out) {
    __shared__ float4 red[256];
    const int tid = threadIdx.x;
    float4 a = make_float4(0.f, 0.f, 0.f, 0.f);
    for (int i = tid; i < n; i += 256) {
        float4 p = partials[i];
        a.x += p.x; a.y += p.y; a.z += p.z; a.w += p.w;
    }
    red[tid] = a;
    __syncthreads();
    for (int s = 128; s > 0; s >>= 1) {
        if (tid < s) {
            red[tid].x += red[tid + s].x; red[tid].y += red[tid + s].y;
            red[tid].z += red[tid + s].z; red[tid].w += red[tid + s].w;
        }
        __syncthreads();
    }
    if (tid == 0) {
        float npt  = red[0].w;
        float conf = red[0].x / npt;
        float loc  = red[0].y / (npt * 4.f);
        float ang  = 25.f * red[0].z / (npt * 2.f);
        out[0] = conf; out[1] = loc; out[2] = ang; out[3] = conf + loc + ang;
    }
}

extern "C" void kernel_launch(void* const* d_in, const int* in_sizes, int n_in,
                              void* d_out, int out_size, void* d_ws, size_t ws_size,
                              hipStream_t stream) {
    const float* locs   = (const float*)d_in[0];
    const float* scores = (const float*)d_in[1];
    const float* target = (const float*)d_in[2];
    const float* priors = (const float*)d_in[3];
    float* out = (float*)d_out;

    const int batch = in_sizes[2] / 8;   // target is (B,1,8)

    int nblk = 2048;
    int max_waves = (int)(ws_size / sizeof(float4));
    if (nblk * WPB > max_waves) nblk = max_waves / WPB;
    if (nblk < 1) nblk = 1;
    const int totw = nblk * WPB;

    float4* partials = (float4*)d_ws;

    mbloss_main<<<nblk, TPB, 0, stream>>>(locs, scores, target, priors,
                                          partials, batch, totw);
    mbloss_fin<<<1, 256, 0, stream>>>(partials, totw, out);
}